// Round 1
// baseline (192.615 us; speedup 1.0000x reference)
//
#include <hip/hip_runtime.h>
#include <hip/hip_bf16.h>
#include <math.h>

#define NTYPE   4
#define NWAVE   8
#define NORBIT  128
#define NEIGH   64
#define NB      32
#define NATOM   256
#define NPP     (NATOM * NEIGH)   /* 16384 pairs per batch */
#define NPAIR   (NB * NPP)        /* 524288 */
#define TOTATOM (NB * NATOM)      /* 8192  */
#define NPARA   13                /* 1 + 3 + 9 */

__device__ __forceinline__ float fast_tanh(float x) {
    float ax = fabsf(x);
    float e  = __expf(-2.0f * ax);
    float r  = (1.0f - e) / (1.0f + e);
    return copysignf(r, x);
}

// ---- init: zero histogram, coeff[a][w] = params[species[a]][w] -------------
__global__ __launch_bounds__(256) void k_init(int* __restrict__ hist,
                                              float* __restrict__ coeff,
                                              const float* __restrict__ params,
                                              const int* __restrict__ species) {
    int a = blockIdx.x * 256 + threadIdx.x;   // grid covers 8192
    hist[a] = 0;
    int sp = species[a];
#pragma unroll
    for (int w = 0; w < NWAVE; w++) coeff[a * NWAVE + w] = params[sp * NWAVE + w];
}

// ---- histogram of center-atom ids ------------------------------------------
__global__ __launch_bounds__(256) void k_hist(const int* __restrict__ atom_index,
                                              int* __restrict__ hist) {
    int p = blockIdx.x * 256 + threadIdx.x;
    int b = p >> 14, k = p & (NPP - 1);
    int i_loc = atom_index[b * NPP + k];           // row 0
    atomicAdd(&hist[b * NATOM + i_loc], 1);
}

// ---- exclusive scan of 8192 counts (single block, 256 thr × 32 each) -------
__global__ __launch_bounds__(256) void k_scan(const int* __restrict__ hist,
                                              int* __restrict__ offs,
                                              int* __restrict__ cursor) {
    __shared__ int part[256];
    int t = threadIdx.x;
    int local[32];
    int s = 0;
#pragma unroll
    for (int k = 0; k < 32; k++) { local[k] = hist[t * 32 + k]; s += local[k]; }
    part[t] = s;
    __syncthreads();
    for (int d = 1; d < 256; d <<= 1) {
        int v = (t >= d) ? part[t - d] : 0;
        __syncthreads();
        part[t] += v;
        __syncthreads();
    }
    int run = (t > 0) ? part[t - 1] : 0;
#pragma unroll
    for (int k = 0; k < 32; k++) {
        offs[t * 32 + k] = run;
        cursor[t * 32 + k] = run;
        run += local[k];
    }
}

// ---- scatter: sorted 16B records {dvec, j|sp<<16} --------------------------
__global__ __launch_bounds__(256) void k_scatter(const int* __restrict__ atom_index,
                                                 const float* __restrict__ cart,
                                                 const float* __restrict__ shifts,
                                                 const int* __restrict__ species,
                                                 int* __restrict__ cursor,
                                                 float4* __restrict__ rec) {
    int p = blockIdx.x * 256 + threadIdx.x;
    int b = p >> 14, k = p & (NPP - 1);
    int i_loc = atom_index[b * NPP + k];
    int j_loc = atom_index[NPAIR + b * NPP + k];   // row 1
    int ig = b * NATOM + i_loc;
    int jg = b * NATOM + j_loc;
    float dx = cart[ig * 3 + 0] - cart[jg * 3 + 0] + shifts[p * 3 + 0];
    float dy = cart[ig * 3 + 1] - cart[jg * 3 + 1] + shifts[p * 3 + 1];
    float dz = cart[ig * 3 + 2] - cart[jg * 3 + 2] + shifts[p * 3 + 2];
    int sp = species[jg];
    int pos = atomicAdd(&cursor[ig], 1);
    rec[pos] = make_float4(dx, dy, dz, __int_as_float(jg | (sp << 16)));
}

// ---- fused obtain(): per-atom wave, 8 pair-lanes × 8 wave-channels ---------
__global__ __launch_bounds__(256) void k_density(const float4* __restrict__ rec,
                                                 const int* __restrict__ offs,
                                                 const int* __restrict__ hist,
                                                 const float* __restrict__ coeff,
                                                 const float* __restrict__ rs,
                                                 const float* __restrict__ inta,
                                                 const float* __restrict__ hyper,
                                                 float* __restrict__ density) {
    const int wv = threadIdx.x >> 6;
    const int lane = threadIdx.x & 63;
    const int a = blockIdx.x * 4 + wv;
    const int pl = lane >> 3;       // pair sub-lane 0..7
    const int w  = lane & 7;        // wave channel 0..7

    const int start = offs[a];
    const int end   = start + hist[a];

    float S[NPARA];
#pragma unroll
    for (int k = 0; k < NPARA; k++) S[k] = 0.0f;

    for (int idx = start + pl; idx < end; idx += 8) {
        float4 r = rec[idx];
        int jp = __float_as_int(r.w);
        int j  = jp & 0xFFFF;
        int sp = jp >> 16;
        float d2 = r.x * r.x + r.y * r.y + r.z * r.z;
        float d  = sqrtf(d2);
        float c  = __cosf(d * 0.62831853071795864769f);   // pi / CUTOFF
        float fc = 0.5f * c + 0.5f;
        fc = fc * fc;
        float dr  = d - rs[sp * NWAVE + w];
        float rad = __expf(inta[sp * NWAVE + w] * dr * dr);
        float rc  = rad * coeff[j * NWAVE + w];

        float q = fc * rc;                 // ang0 * rc
        S[0] += q;
        float qx = q * r.x, qy = q * r.y, qz = q * r.z;
        S[1] += qx; S[2] += qy; S[3] += qz;
        S[4]  += qx * r.x; S[5]  += qx * r.y; S[6]  += qx * r.z;
        S[7]  += qy * r.x; S[8]  += qy * r.y; S[9]  += qy * r.z;
        S[10] += qz * r.x; S[11] += qz * r.y; S[12] += qz * r.z;
    }

    // reduce over the 8 pair sub-lanes (lanes sharing w differ in bits 3..5)
#pragma unroll
    for (int k = 0; k < NPARA; k++) {
        S[k] += __shfl_xor(S[k], 8, 64);
        S[k] += __shfl_xor(S[k], 16, 64);
        S[k] += __shfl_xor(S[k], 32, 64);
    }

    __shared__ float lds_S[4][NPARA * NWAVE];
    if (pl == 0) {
#pragma unroll
        for (int k = 0; k < NPARA; k++) lds_S[wv][k * NWAVE + w] = S[k];
    }
    __syncthreads();

    // projection: hw[para][o] = sum_w S[para][w] * H[para][w][o]; density = sum_para hw^2
    float acc0 = 0.0f, acc1 = 0.0f;
    const int o0 = lane, o1 = lane + 64;
#pragma unroll
    for (int para = 0; para < NPARA; para++) {
        int ip = (para == 0) ? 0 : ((para < 4) ? 1 : 2);
        const float* Hb = hyper + ip * NWAVE * NORBIT;
        float h0 = 0.0f, h1 = 0.0f;
#pragma unroll
        for (int w2 = 0; w2 < NWAVE; w2++) {
            float s = lds_S[wv][para * NWAVE + w2];
            h0 += s * Hb[w2 * NORBIT + o0];
            h1 += s * Hb[w2 * NORBIT + o1];
        }
        acc0 += h0 * h0;
        acc1 += h1 * h1;
    }
    density[a * NORBIT + o0] = acc0;
    density[a * NORBIT + o1] = acc1;
}

// ---- coeff update: coeff += tanh(density @ W + E[species]) -----------------
__global__ __launch_bounds__(256) void k_update(const float* __restrict__ density,
                                                const float* __restrict__ W,
                                                const float* __restrict__ E,
                                                const int* __restrict__ species,
                                                float* __restrict__ coeff) {
    const int wv = threadIdx.x >> 6;
    const int lane = threadIdx.x & 63;
    const int a = blockIdx.x * 4 + wv;
    const int oc = lane >> 3;
    const int w  = lane & 7;
    float sum = 0.0f;
#pragma unroll
    for (int t = 0; t < 16; t++) {
        int o = oc + 8 * t;
        sum += density[a * NORBIT + o] * W[o * NWAVE + w];
    }
    sum += __shfl_xor(sum, 8, 64);
    sum += __shfl_xor(sum, 16, 64);
    sum += __shfl_xor(sum, 32, 64);
    if (oc == 0) {
        int sp = species[a];
        coeff[a * NWAVE + w] += fast_tanh(sum + E[sp * NWAVE + w]);
    }
}

extern "C" void kernel_launch(void* const* d_in, const int* in_sizes, int n_in,
                              void* d_out, int out_size, void* d_ws, size_t ws_size,
                              hipStream_t stream) {
    const float* cart    = (const float*)d_in[0];
    const float* shifts  = (const float*)d_in[1];
    const float* rs      = (const float*)d_in[2];
    const float* inta    = (const float*)d_in[3];
    const float* params  = (const float*)d_in[4];
    const float* hyper   = (const float*)d_in[5];
    const float* w0      = (const float*)d_in[6];
    const float* e0      = (const float*)d_in[7];
    const float* w1      = (const float*)d_in[8];
    const float* e1      = (const float*)d_in[9];
    // d_in[10] = numatoms (unused, always NATOM)
    const int* species    = (const int*)d_in[11];
    const int* atom_index = (const int*)d_in[12];
    float* out = (float*)d_out;

    char* ws = (char*)d_ws;
    float4* rec  = (float4*)ws;               ws += (size_t)NPAIR * 16;      // 8 MiB
    float*  dtmp = (float*)ws;                ws += (size_t)TOTATOM * NORBIT * 4; // 4 MiB
    float*  coeff = (float*)ws;               ws += (size_t)TOTATOM * NWAVE * 4;  // 256 KiB
    int* hist   = (int*)ws;                   ws += TOTATOM * 4;
    int* offs   = (int*)ws;                   ws += TOTATOM * 4;
    int* cursor = (int*)ws;                   ws += TOTATOM * 4;

    k_init<<<TOTATOM / 256, 256, 0, stream>>>(hist, coeff, params, species);
    k_hist<<<NPAIR / 256, 256, 0, stream>>>(atom_index, hist);
    k_scan<<<1, 256, 0, stream>>>(hist, offs, cursor);
    k_scatter<<<NPAIR / 256, 256, 0, stream>>>(atom_index, cart, shifts, species, cursor, rec);

    k_density<<<TOTATOM / 4, 256, 0, stream>>>(rec, offs, hist, coeff, rs, inta, hyper, dtmp);
    k_update<<<TOTATOM / 4, 256, 0, stream>>>(dtmp, w0, e0, species, coeff);
    k_density<<<TOTATOM / 4, 256, 0, stream>>>(rec, offs, hist, coeff, rs, inta, hyper, dtmp);
    k_update<<<TOTATOM / 4, 256, 0, stream>>>(dtmp, w1, e1, species, coeff);
    k_density<<<TOTATOM / 4, 256, 0, stream>>>(rec, offs, hist, coeff, rs, inta, hyper, out);
}

// Round 2
// 170.701 us; speedup vs baseline: 1.1284x; 1.1284x over previous
//
#include <hip/hip_runtime.h>
#include <hip/hip_bf16.h>
#include <math.h>

#define NTYPE   4
#define NWAVE   8
#define NORBIT  128
#define NEIGH   64
#define NB      32
#define NATOM   256
#define NPP     (NATOM * NEIGH)   /* 16384 pairs per batch */
#define NPAIR   (NB * NPP)        /* 524288 */
#define TOTATOM (NB * NATOM)      /* 8192  */
#define NPARA   13                /* 1 + 3 + 9 */

__device__ __forceinline__ float fast_tanh(float x) {
    float ax = fabsf(x);
    float e  = __expf(-2.0f * ax);
    float r  = (1.0f - e) / (1.0f + e);
    return copysignf(r, x);
}

// ---- one block per batch: init coeff, LDS histogram + scan + scatter -------
__global__ __launch_bounds__(1024) void k_sort(const int* __restrict__ atom_index,
                                               const float* __restrict__ cart,
                                               const float* __restrict__ shifts,
                                               const int* __restrict__ species,
                                               const float* __restrict__ params,
                                               float* __restrict__ coeff0,
                                               float4* __restrict__ rec,
                                               int* __restrict__ offs) {
    const int b = blockIdx.x;
    const int t = threadIdx.x;
    __shared__ int hist[NATOM];
    __shared__ int scan[NATOM];
    __shared__ int cur[NATOM];

    if (t < NATOM) {
        hist[t] = 0;
        int a = b * NATOM + t;
        int sp = species[a];
#pragma unroll
        for (int w = 0; w < NWAVE; w++) coeff0[a * NWAVE + w] = params[sp * NWAVE + w];
    }
    __syncthreads();

    int iloc[16];
#pragma unroll
    for (int k = 0; k < 16; k++) {
        int p = t + k * 1024;
        iloc[k] = atom_index[b * NPP + p];              // row 0 (center)
        atomicAdd(&hist[iloc[k]], 1);
    }
    __syncthreads();

    if (t < NATOM) scan[t] = hist[t];
    __syncthreads();
    for (int d = 1; d < NATOM; d <<= 1) {
        int v = (t < NATOM && t >= d) ? scan[t - d] : 0;
        __syncthreads();
        if (t < NATOM) scan[t] += v;
        __syncthreads();
    }
    if (t < NATOM) {
        int ex = scan[t] - hist[t];                     // exclusive prefix
        cur[t] = ex;
        offs[b * NATOM + t] = b * NPP + ex;
    }
    if (b == NB - 1 && t == 0) offs[TOTATOM] = NPAIR;
    __syncthreads();

#pragma unroll
    for (int k = 0; k < 16; k++) {
        int p = t + k * 1024;
        int i = iloc[k];
        int jloc = atom_index[NPAIR + b * NPP + p];     // row 1 (neighbor)
        int ig = b * NATOM + i;
        int jg = b * NATOM + jloc;
        float dx = cart[ig * 3 + 0] - cart[jg * 3 + 0] + shifts[(b * NPP + p) * 3 + 0];
        float dy = cart[ig * 3 + 1] - cart[jg * 3 + 1] + shifts[(b * NPP + p) * 3 + 1];
        float dz = cart[ig * 3 + 2] - cart[jg * 3 + 2] + shifts[(b * NPP + p) * 3 + 2];
        int sp = species[jg];
        int pos = atomicAdd(&cur[i], 1);
        rec[b * NPP + pos] = make_float4(dx, dy, dz, __int_as_float(jg | (sp << 16)));
    }
}

// ---- fused obtain() + coeff update -----------------------------------------
// mode 0: coeff_out = coeff_in + tanh(density @ W + E[species])   (density stays in regs)
// mode 1: write density to density_out
__global__ __launch_bounds__(256) void k_density(const float4* __restrict__ rec,
                                                 const int* __restrict__ offs,
                                                 const float* __restrict__ coeff_in,
                                                 const float* __restrict__ rs,
                                                 const float* __restrict__ inta,
                                                 const float* __restrict__ hyper,
                                                 const float* __restrict__ W,
                                                 const float* __restrict__ E,
                                                 const int* __restrict__ species,
                                                 float* __restrict__ coeff_out,
                                                 float* __restrict__ density_out,
                                                 int mode) {
    const int wv = threadIdx.x >> 6;
    const int lane = threadIdx.x & 63;
    const int a = blockIdx.x * 4 + wv;
    const int pl = lane >> 3;       // pair sub-lane 0..7
    const int w  = lane & 7;        // wave channel 0..7

    // register-resident radial tables for this lane's w (select by species)
    float rs0 = rs[0 * NWAVE + w], rs1 = rs[1 * NWAVE + w],
          rs2 = rs[2 * NWAVE + w], rs3 = rs[3 * NWAVE + w];
    float in0 = inta[0 * NWAVE + w], in1 = inta[1 * NWAVE + w],
          in2 = inta[2 * NWAVE + w], in3 = inta[3 * NWAVE + w];

    const int start = offs[a];
    const int end   = offs[a + 1];

    float S[NPARA];
#pragma unroll
    for (int k = 0; k < NPARA; k++) S[k] = 0.0f;

#pragma unroll 2
    for (int idx = start + pl; idx < end; idx += 8) {
        float4 r = rec[idx];
        int jp = __float_as_int(r.w);
        int j  = jp & 0xFFFF;
        int sp = jp >> 16;
        float cj = coeff_in[j * NWAVE + w];             // issue gather early
        float d2 = r.x * r.x + r.y * r.y + r.z * r.z;
        float d  = sqrtf(d2);
        float c  = __cosf(d * 0.62831853071795864769f); // pi / CUTOFF
        float fc = 0.5f * c + 0.5f;
        fc = fc * fc;
        float rw = (sp == 0) ? rs0 : (sp == 1) ? rs1 : (sp == 2) ? rs2 : rs3;
        float iw = (sp == 0) ? in0 : (sp == 1) ? in1 : (sp == 2) ? in2 : in3;
        float dr  = d - rw;
        float rad = __expf(iw * dr * dr);
        float q = fc * rad * cj;
        S[0] += q;
        float qx = q * r.x, qy = q * r.y, qz = q * r.z;
        S[1] += qx; S[2] += qy; S[3] += qz;
        S[4]  += qx * r.x; S[5]  += qx * r.y; S[6]  += qx * r.z;
        S[7]  += qy * r.x; S[8]  += qy * r.y; S[9]  += qy * r.z;
        S[10] += qz * r.x; S[11] += qz * r.y; S[12] += qz * r.z;
    }

    // reduce over the 8 pair sub-lanes (lanes sharing w differ in bits 3..5)
#pragma unroll
    for (int k = 0; k < NPARA; k++) {
        S[k] += __shfl_xor(S[k], 8, 64);
        S[k] += __shfl_xor(S[k], 16, 64);
        S[k] += __shfl_xor(S[k], 32, 64);
    }

    __shared__ float lds_S[4][NPARA * NWAVE];
    if (pl == 0) {
#pragma unroll
        for (int k = 0; k < NPARA; k++) lds_S[wv][k * NWAVE + w] = S[k];
    }
    __syncthreads();

    // projection: hw[para][o] = sum_w S[para][w]*H[para][w][o]; density = sum_para hw^2
    float acc0 = 0.0f, acc1 = 0.0f;
    const int o0 = lane, o1 = lane + 64;
#pragma unroll
    for (int para = 0; para < NPARA; para++) {
        int ip = (para == 0) ? 0 : ((para < 4) ? 1 : 2);
        const float* Hb = hyper + ip * NWAVE * NORBIT;
        float h0 = 0.0f, h1 = 0.0f;
#pragma unroll
        for (int w2 = 0; w2 < NWAVE; w2++) {
            float s = lds_S[wv][para * NWAVE + w2];
            h0 += s * Hb[w2 * NORBIT + o0];
            h1 += s * Hb[w2 * NORBIT + o1];
        }
        acc0 += h0 * h0;
        acc1 += h1 * h1;
    }

    if (mode == 1) {
        density_out[a * NORBIT + o0] = acc0;
        density_out[a * NORBIT + o1] = acc1;
        return;
    }

    // fused coeff update: part[w] = sum_o density[o] * W[o][w]
    float part[NWAVE];
#pragma unroll
    for (int w2 = 0; w2 < NWAVE; w2++)
        part[w2] = acc0 * W[o0 * NWAVE + w2] + acc1 * W[o1 * NWAVE + w2];
#pragma unroll
    for (int mask = 1; mask < 64; mask <<= 1) {
#pragma unroll
        for (int w2 = 0; w2 < NWAVE; w2++)
            part[w2] += __shfl_xor(part[w2], mask, 64);
    }
    if (lane < NWAVE) {
        int sp = species[a];
        coeff_out[a * NWAVE + lane] =
            coeff_in[a * NWAVE + lane] + fast_tanh(part[lane] + E[sp * NWAVE + lane]);
    }
}

extern "C" void kernel_launch(void* const* d_in, const int* in_sizes, int n_in,
                              void* d_out, int out_size, void* d_ws, size_t ws_size,
                              hipStream_t stream) {
    const float* cart    = (const float*)d_in[0];
    const float* shifts  = (const float*)d_in[1];
    const float* rs      = (const float*)d_in[2];
    const float* inta    = (const float*)d_in[3];
    const float* params  = (const float*)d_in[4];
    const float* hyper   = (const float*)d_in[5];
    const float* w0      = (const float*)d_in[6];
    const float* e0      = (const float*)d_in[7];
    const float* w1      = (const float*)d_in[8];
    const float* e1      = (const float*)d_in[9];
    // d_in[10] = numatoms (unused, always NATOM)
    const int* species    = (const int*)d_in[11];
    const int* atom_index = (const int*)d_in[12];
    float* out = (float*)d_out;

    char* ws = (char*)d_ws;
    float4* rec   = (float4*)ws;  ws += (size_t)NPAIR * 16;            // 8 MiB
    float* coeffA = (float*)ws;   ws += (size_t)TOTATOM * NWAVE * 4;   // 256 KiB
    float* coeffB = (float*)ws;   ws += (size_t)TOTATOM * NWAVE * 4;   // 256 KiB
    int* offs     = (int*)ws;     ws += (TOTATOM + 1) * 4;

    k_sort<<<NB, 1024, 0, stream>>>(atom_index, cart, shifts, species, params,
                                    coeffA, rec, offs);

    k_density<<<TOTATOM / 4, 256, 0, stream>>>(rec, offs, coeffA, rs, inta, hyper,
                                               w0, e0, species, coeffB, out, 0);
    k_density<<<TOTATOM / 4, 256, 0, stream>>>(rec, offs, coeffB, rs, inta, hyper,
                                               w1, e1, species, coeffA, out, 0);
    k_density<<<TOTATOM / 4, 256, 0, stream>>>(rec, offs, coeffA, rs, inta, hyper,
                                               w1, e1, species, coeffB, out, 1);
}

// Round 3
// 148.892 us; speedup vs baseline: 1.2937x; 1.1465x over previous
//
#include <hip/hip_runtime.h>
#include <hip/hip_bf16.h>
#include <math.h>

#define NTYPE   4
#define NWAVE   8
#define NORBIT  128
#define NEIGH   64
#define NB      32
#define NATOM   256
#define NPP     (NATOM * NEIGH)   /* 16384 pairs per batch */
#define NPAIR   (NB * NPP)        /* 524288 */
#define TOTATOM (NB * NATOM)      /* 8192  */
#define NPARA   13                /* 1 + 3 + 9 */

#define CHUNK   2048              /* pairs per sort block */
#define BPB     8                 /* sort blocks per batch */
#define NBLK    (NB * BPB)        /* 256 sort blocks */

__device__ __forceinline__ float fast_tanh(float x) {
    float ax = fabsf(x);
    float e  = __expf(-2.0f * ax);
    float r  = (1.0f - e) / (1.0f + e);
    return copysignf(r, x);
}

// ---- per-chunk LDS histogram -> histpart[block][256] ------------------------
__global__ __launch_bounds__(256) void k_hist(const int* __restrict__ atom_index,
                                              int* __restrict__ histpart) {
    const int bl = blockIdx.x, t = threadIdx.x;
    const int b = bl >> 3, c = bl & 7;
    __shared__ int hist[NATOM];
    hist[t] = 0;
    __syncthreads();
    const int base = b * NPP + c * CHUNK;
#pragma unroll
    for (int k = 0; k < CHUNK / 256; k++) {
        int i = atom_index[base + t + k * 256];
        atomicAdd(&hist[i], 1);
    }
    __syncthreads();
    histpart[bl * NATOM + t] = hist[t];
}

// ---- per-batch: merge chunk hists, scan bins, emit per-chunk start cursors --
__global__ __launch_bounds__(256) void k_offsets(const int* __restrict__ histpart,
                                                 int* __restrict__ startpart,
                                                 int* __restrict__ offs,
                                                 const int* __restrict__ species,
                                                 const float* __restrict__ params,
                                                 float* __restrict__ coeff0) {
    const int b = blockIdx.x, t = threadIdx.x;
    int h[BPB];
    int tot = 0;
#pragma unroll
    for (int c = 0; c < BPB; c++) {
        h[c] = histpart[(b * BPB + c) * NATOM + t];
        tot += h[c];
    }
    __shared__ int scan[NATOM];
    scan[t] = tot;
    __syncthreads();
    for (int d = 1; d < NATOM; d <<= 1) {
        int v = (t >= d) ? scan[t - d] : 0;
        __syncthreads();
        scan[t] += v;
        __syncthreads();
    }
    int run = b * NPP + (scan[t] - tot);   // exclusive prefix within batch
    offs[b * NATOM + t] = run;
    if (b == 0 && t == 0) offs[TOTATOM] = NPAIR;
#pragma unroll
    for (int c = 0; c < BPB; c++) {
        startpart[(b * BPB + c) * NATOM + t] = run;
        run += h[c];
    }
    // coeff init
    int a = b * NATOM + t;
    int sp = species[a];
#pragma unroll
    for (int w = 0; w < NWAVE; w++) coeff0[a * NWAVE + w] = params[sp * NWAVE + w];
}

// ---- per-chunk scatter using LDS cursors + LDS-cached cart/species ----------
__global__ __launch_bounds__(256) void k_scatter(const int* __restrict__ atom_index,
                                                 const float* __restrict__ cart,
                                                 const float* __restrict__ shifts,
                                                 const int* __restrict__ species,
                                                 const int* __restrict__ startpart,
                                                 float4* __restrict__ rec) {
    const int bl = blockIdx.x, t = threadIdx.x;
    const int b = bl >> 3, c = bl & 7;
    __shared__ int cur[NATOM];
    __shared__ float cx[NATOM], cy[NATOM], cz[NATOM];
    __shared__ int spl[NATOM];
    cur[t] = startpart[bl * NATOM + t];
    const int ag = b * NATOM + t;
    cx[t] = cart[ag * 3 + 0];
    cy[t] = cart[ag * 3 + 1];
    cz[t] = cart[ag * 3 + 2];
    spl[t] = species[ag];
    __syncthreads();
    const int base = b * NPP + c * CHUNK;
#pragma unroll
    for (int k = 0; k < CHUNK / 256; k++) {
        int p = base + t + k * 256;
        int i = atom_index[p];
        int j = atom_index[NPAIR + p];
        float dx = cx[i] - cx[j] + shifts[p * 3 + 0];
        float dy = cy[i] - cy[j] + shifts[p * 3 + 1];
        float dz = cz[i] - cz[j] + shifts[p * 3 + 2];
        int jg = b * NATOM + j;
        int pos = atomicAdd(&cur[i], 1);
        rec[pos] = make_float4(dx, dy, dz, __int_as_float(jg | (spl[j] << 16)));
    }
}

// ---- fused obtain() + coeff update -----------------------------------------
// mode 0: coeff_out = coeff_in + tanh(density @ W + E[species])
// mode 1: write density to density_out
__global__ __launch_bounds__(256) void k_density(const float4* __restrict__ rec,
                                                 const int* __restrict__ offs,
                                                 const float* __restrict__ coeff_in,
                                                 const float* __restrict__ rs,
                                                 const float* __restrict__ inta,
                                                 const float* __restrict__ hyper,
                                                 const float* __restrict__ W,
                                                 const float* __restrict__ E,
                                                 const int* __restrict__ species,
                                                 float* __restrict__ coeff_out,
                                                 float* __restrict__ density_out,
                                                 int mode) {
    const int wv = threadIdx.x >> 6;
    const int lane = threadIdx.x & 63;
    const int a = blockIdx.x * 4 + wv;
    const int pl = lane >> 3;       // pair sub-lane 0..7
    const int w  = lane & 7;        // wave channel 0..7

    // register-resident radial tables for this lane's w (select by species)
    float rs0 = rs[w],      rs1 = rs[8 + w],  rs2 = rs[16 + w], rs3 = rs[24 + w];
    float in0 = inta[w],    in1 = inta[8 + w], in2 = inta[16 + w], in3 = inta[24 + w];

    const int start = offs[a];
    const int end   = offs[a + 1];

    float S[NPARA];
#pragma unroll
    for (int k = 0; k < NPARA; k++) S[k] = 0.0f;

    int idx = start + pl;
    float4 r = make_float4(0.f, 0.f, 0.f, 0.f);
    if (idx < end) r = rec[idx];
    for (; idx < end; idx += 8) {
        int nidx = idx + 8;
        float4 rn = r;
        if (nidx < end) rn = rec[nidx];           // prefetch next record
        int jp = __float_as_int(r.w);
        int j  = jp & 0xFFFF;
        int sp = jp >> 16;
        float cj = coeff_in[j * NWAVE + w];       // gather (L1/L2)
        float d2 = r.x * r.x + r.y * r.y + r.z * r.z;
        float d  = sqrtf(d2);
        float c  = __cosf(d * 0.62831853071795864769f); // pi / CUTOFF
        float fc = 0.5f * c + 0.5f;
        fc = fc * fc;
        float rw = (sp == 0) ? rs0 : (sp == 1) ? rs1 : (sp == 2) ? rs2 : rs3;
        float iw = (sp == 0) ? in0 : (sp == 1) ? in1 : (sp == 2) ? in2 : in3;
        float dr  = d - rw;
        float rad = __expf(iw * dr * dr);
        float q = fc * rad * cj;
        S[0] += q;
        float qx = q * r.x, qy = q * r.y, qz = q * r.z;
        S[1] += qx; S[2] += qy; S[3] += qz;
        S[4]  += qx * r.x; S[5]  += qx * r.y; S[6]  += qx * r.z;
        S[7]  += qy * r.x; S[8]  += qy * r.y; S[9]  += qy * r.z;
        S[10] += qz * r.x; S[11] += qz * r.y; S[12] += qz * r.z;
        r = rn;
    }

    // reduce over the 8 pair sub-lanes (lanes sharing w differ in bits 3..5)
#pragma unroll
    for (int k = 0; k < NPARA; k++) {
        S[k] += __shfl_xor(S[k], 8, 64);
        S[k] += __shfl_xor(S[k], 16, 64);
        S[k] += __shfl_xor(S[k], 32, 64);
    }

    // transposed stash: lds_S[wv][w*16 + para]  (stride 16 -> b128-aligned rows)
    __shared__ float lds_S[4][NWAVE * 16];
    if (pl == 0) {
#pragma unroll
        for (int k = 0; k < NPARA; k++) lds_S[wv][w * 16 + k] = S[k];
    }
    __syncthreads();

    // projection with hw-accumulators: hyper read once per (w,ip) -> 48 loads
    const int o0 = lane, o1 = lane + 64;
    float hw0[NPARA], hw1[NPARA];
#pragma unroll
    for (int k = 0; k < NPARA; k++) { hw0[k] = 0.0f; hw1[k] = 0.0f; }
#pragma unroll
    for (int w2 = 0; w2 < NWAVE; w2++) {
        const float* Sw = &lds_S[wv][w2 * 16];
        float4 s0 = *(const float4*)(Sw);        // S[0..3]  (broadcast ds_read_b128)
        float4 s1 = *(const float4*)(Sw + 4);    // S[4..7]
        float4 s2 = *(const float4*)(Sw + 8);    // S[8..11]
        float  sc = Sw[12];                      // S[12]
        float h00 = hyper[w2 * NORBIT + o0];
        float h01 = hyper[w2 * NORBIT + o1];
        float h10 = hyper[(NWAVE + w2) * NORBIT + o0];
        float h11 = hyper[(NWAVE + w2) * NORBIT + o1];
        float h20 = hyper[(2 * NWAVE + w2) * NORBIT + o0];
        float h21 = hyper[(2 * NWAVE + w2) * NORBIT + o1];
        hw0[0]  += s0.x * h00; hw1[0]  += s0.x * h01;
        hw0[1]  += s0.y * h10; hw1[1]  += s0.y * h11;
        hw0[2]  += s0.z * h10; hw1[2]  += s0.z * h11;
        hw0[3]  += s0.w * h10; hw1[3]  += s0.w * h11;
        hw0[4]  += s1.x * h20; hw1[4]  += s1.x * h21;
        hw0[5]  += s1.y * h20; hw1[5]  += s1.y * h21;
        hw0[6]  += s1.z * h20; hw1[6]  += s1.z * h21;
        hw0[7]  += s1.w * h20; hw1[7]  += s1.w * h21;
        hw0[8]  += s2.x * h20; hw1[8]  += s2.x * h21;
        hw0[9]  += s2.y * h20; hw1[9]  += s2.y * h21;
        hw0[10] += s2.z * h20; hw1[10] += s2.z * h21;
        hw0[11] += s2.w * h20; hw1[11] += s2.w * h21;
        hw0[12] += sc   * h20; hw1[12] += sc   * h21;
    }
    float acc0 = 0.0f, acc1 = 0.0f;
#pragma unroll
    for (int k = 0; k < NPARA; k++) {
        acc0 += hw0[k] * hw0[k];
        acc1 += hw1[k] * hw1[k];
    }

    if (mode == 1) {
        density_out[a * NORBIT + o0] = acc0;
        density_out[a * NORBIT + o1] = acc1;
        return;
    }

    // fused coeff update: part[w] = sum_o density[o] * W[o][w]
    float part[NWAVE];
#pragma unroll
    for (int w2 = 0; w2 < NWAVE; w2++)
        part[w2] = acc0 * W[o0 * NWAVE + w2] + acc1 * W[o1 * NWAVE + w2];
#pragma unroll
    for (int mask = 1; mask < 64; mask <<= 1) {
#pragma unroll
        for (int w2 = 0; w2 < NWAVE; w2++)
            part[w2] += __shfl_xor(part[w2], mask, 64);
    }
    if (lane < NWAVE) {
        int sp = species[a];
        coeff_out[a * NWAVE + lane] =
            coeff_in[a * NWAVE + lane] + fast_tanh(part[lane] + E[sp * NWAVE + lane]);
    }
}

extern "C" void kernel_launch(void* const* d_in, const int* in_sizes, int n_in,
                              void* d_out, int out_size, void* d_ws, size_t ws_size,
                              hipStream_t stream) {
    const float* cart    = (const float*)d_in[0];
    const float* shifts  = (const float*)d_in[1];
    const float* rs      = (const float*)d_in[2];
    const float* inta    = (const float*)d_in[3];
    const float* params  = (const float*)d_in[4];
    const float* hyper   = (const float*)d_in[5];
    const float* w0      = (const float*)d_in[6];
    const float* e0      = (const float*)d_in[7];
    const float* w1      = (const float*)d_in[8];
    const float* e1      = (const float*)d_in[9];
    // d_in[10] = numatoms (unused, always NATOM)
    const int* species    = (const int*)d_in[11];
    const int* atom_index = (const int*)d_in[12];
    float* out = (float*)d_out;

    char* ws = (char*)d_ws;
    float4* rec    = (float4*)ws;  ws += (size_t)NPAIR * 16;            // 8 MiB
    float* coeffA  = (float*)ws;   ws += (size_t)TOTATOM * NWAVE * 4;   // 256 KiB
    float* coeffB  = (float*)ws;   ws += (size_t)TOTATOM * NWAVE * 4;   // 256 KiB
    int* offs      = (int*)ws;     ws += (TOTATOM + 1) * 4;
    ws = (char*)(((uintptr_t)ws + 255) & ~(uintptr_t)255);
    int* histpart  = (int*)ws;     ws += (size_t)NBLK * NATOM * 4;      // 256 KiB
    int* startpart = (int*)ws;     ws += (size_t)NBLK * NATOM * 4;      // 256 KiB

    k_hist<<<NBLK, 256, 0, stream>>>(atom_index, histpart);
    k_offsets<<<NB, 256, 0, stream>>>(histpart, startpart, offs, species, params, coeffA);
    k_scatter<<<NBLK, 256, 0, stream>>>(atom_index, cart, shifts, species, startpart, rec);

    k_density<<<TOTATOM / 4, 256, 0, stream>>>(rec, offs, coeffA, rs, inta, hyper,
                                               w0, e0, species, coeffB, out, 0);
    k_density<<<TOTATOM / 4, 256, 0, stream>>>(rec, offs, coeffB, rs, inta, hyper,
                                               w1, e1, species, coeffA, out, 0);
    k_density<<<TOTATOM / 4, 256, 0, stream>>>(rec, offs, coeffA, rs, inta, hyper,
                                               w1, e1, species, coeffB, out, 1);
}